// Round 10
// baseline (172.334 us; speedup 1.0000x reference)
//
#include <hip/hip_runtime.h>
#include <hip/hip_bf16.h>

typedef __attribute__((ext_vector_type(8))) short short8v;
typedef __attribute__((ext_vector_type(4))) float f32x4;

static constexpr int B_ = 4, S_ = 2048, E_ = 768, H_ = 12, D_ = 64;
static constexpr int NROWS = B_ * H_ * S_;       // 98304
static constexpr float LOG2E = 1.44269504088896340736f;
static constexpr float LN2 = 0.69314718055994530942f;

typedef __attribute__((address_space(3))) unsigned int lds_u32;
typedef const __attribute__((address_space(1))) unsigned int glb_u32;

__device__ __forceinline__ void gload16(const void* g, void* l) {
  __builtin_amdgcn_global_load_lds((glb_u32*)g, (lds_u32*)l, 16, 0, 0);
}

#define VM0 asm volatile("s_waitcnt vmcnt(0)" ::: "memory")
#define VM4 asm volatile("s_waitcnt vmcnt(4)" ::: "memory")
#define VM8 asm volatile("s_waitcnt vmcnt(8)" ::: "memory")
#define LG0 asm volatile("s_waitcnt lgkmcnt(0)" ::: "memory")
#define BAR __builtin_amdgcn_s_barrier()

__device__ __forceinline__ unsigned short f2bf(float f) {
  union { float f; unsigned int u; } v; v.f = f;
  unsigned int u = v.u;
  unsigned int r = (u + 0x7fffu + ((u >> 16) & 1u)) >> 16;
  return (unsigned short)r;
}

// wb[1536][768]: rows 0..767 = beta[h]*log2e*W^Q; rows 768..1535 = W^K
__global__ __launch_bounds__(256) void cvt_w_kernel(const float4* __restrict__ wq,
                                                    const float4* __restrict__ wk,
                                                    const float* __restrict__ beta,
                                                    ushort4* __restrict__ wb, int n4) {
  int i = blockIdx.x * 256 + threadIdx.x;
  if (i < n4) {
    int row = i / (E_ / 4);
    float sc = beta[row >> 6] * LOG2E;
    float4 v = wq[i];
    ushort4 o;
    o.x = f2bf(v.x * sc); o.y = f2bf(v.y * sc); o.z = f2bf(v.z * sc); o.w = f2bf(v.w * sc);
    wb[i] = o;
  } else if (i < 2 * n4) {
    int j = i - n4;
    float4 v = wk[j];
    ushort4 o;
    o.x = f2bf(v.x); o.y = f2bf(v.y); o.z = f2bf(v.z); o.w = f2bf(v.w);
    wb[i] = o;
  }
}

// GEMM: C[8192,1536] = X[8192,768] * W[1536,768]^T, 128x128 tile, BK=64.
// (r9's best: 2-barrier schedule, barriers halved vs BK=32, grid-limited
// 3 blocks/CU so 32KB LDS is free; counted waits never drain to 0 until
// the last step. Byte-identical to r9.)
__global__ __launch_bounds__(256, 3) void proj_kernel(const float* __restrict__ x,
                                                      const unsigned short* __restrict__ wb,
                                                      unsigned short* __restrict__ Qb,
                                                      unsigned short* __restrict__ Kb) {
  __shared__ unsigned short lA[128 * 64];       // 16 KB bf16
  __shared__ unsigned short lB[128 * 64];       // 16 KB bf16
  const int mt = blockIdx.x, nt = blockIdx.y;
  const int t = threadIdx.x;
  const int wid = t >> 6, lane = t & 63, l15 = lane & 15, lhi = lane >> 4;
  const int wr = (wid >> 1) * 64, wc = (wid & 1) * 64;

  f32x4 acc[4][4] = {};

  const int r0 = t >> 3;                        // 0..31
  const int cs = (t & 7) ^ (r0 & 7);            // inverse-swizzled source chunk
  const float* gA = x + (size_t)(mt * 128 + r0) * E_ + cs * 8;
  const unsigned short* gB = wb + (size_t)(nt * 128 + r0) * E_ + cs * 8;

  f32x4 a0 = *(const f32x4*)(gA);
  f32x4 a1 = *(const f32x4*)(gA + 4);
  f32x4 a2 = *(const f32x4*)(gA + 32 * E_);
  f32x4 a3 = *(const f32x4*)(gA + 32 * E_ + 4);
  f32x4 a4 = *(const f32x4*)(gA + 64 * E_);
  f32x4 a5 = *(const f32x4*)(gA + 64 * E_ + 4);
  f32x4 a6 = *(const f32x4*)(gA + 96 * E_);
  f32x4 a7 = *(const f32x4*)(gA + 96 * E_ + 4);

#pragma unroll 1
  for (int i = 0; i < 12; ++i) {
    const int k0 = i * 64;
    BAR;                                        // compute(i-1) done: lA/lB reusable
    gload16(gB + k0,            &lB[t * 8]);
    gload16(gB + 32 * E_ + k0,  &lB[2048 + t * 8]);
    gload16(gB + 64 * E_ + k0,  &lB[4096 + t * 8]);
    gload16(gB + 96 * E_ + k0,  &lB[6144 + t * 8]);
    VM4;                                        // a(i) landed; B(i) in flight
    union { short8v s8; unsigned int u[4]; } c0, c1, c2, c3;
    asm("v_cvt_pk_bf16_f32 %0, %1, %2" : "=v"(c0.u[0]) : "v"(a0[0]), "v"(a0[1]));
    asm("v_cvt_pk_bf16_f32 %0, %1, %2" : "=v"(c0.u[1]) : "v"(a0[2]), "v"(a0[3]));
    asm("v_cvt_pk_bf16_f32 %0, %1, %2" : "=v"(c0.u[2]) : "v"(a1[0]), "v"(a1[1]));
    asm("v_cvt_pk_bf16_f32 %0, %1, %2" : "=v"(c0.u[3]) : "v"(a1[2]), "v"(a1[3]));
    asm("v_cvt_pk_bf16_f32 %0, %1, %2" : "=v"(c1.u[0]) : "v"(a2[0]), "v"(a2[1]));
    asm("v_cvt_pk_bf16_f32 %0, %1, %2" : "=v"(c1.u[1]) : "v"(a2[2]), "v"(a2[3]));
    asm("v_cvt_pk_bf16_f32 %0, %1, %2" : "=v"(c1.u[2]) : "v"(a3[0]), "v"(a3[1]));
    asm("v_cvt_pk_bf16_f32 %0, %1, %2" : "=v"(c1.u[3]) : "v"(a3[2]), "v"(a3[3]));
    asm("v_cvt_pk_bf16_f32 %0, %1, %2" : "=v"(c2.u[0]) : "v"(a4[0]), "v"(a4[1]));
    asm("v_cvt_pk_bf16_f32 %0, %1, %2" : "=v"(c2.u[1]) : "v"(a4[2]), "v"(a4[3]));
    asm("v_cvt_pk_bf16_f32 %0, %1, %2" : "=v"(c2.u[2]) : "v"(a5[0]), "v"(a5[1]));
    asm("v_cvt_pk_bf16_f32 %0, %1, %2" : "=v"(c2.u[3]) : "v"(a5[2]), "v"(a5[3]));
    asm("v_cvt_pk_bf16_f32 %0, %1, %2" : "=v"(c3.u[0]) : "v"(a6[0]), "v"(a6[1]));
    asm("v_cvt_pk_bf16_f32 %0, %1, %2" : "=v"(c3.u[1]) : "v"(a6[2]), "v"(a6[3]));
    asm("v_cvt_pk_bf16_f32 %0, %1, %2" : "=v"(c3.u[2]) : "v"(a7[0]), "v"(a7[1]));
    asm("v_cvt_pk_bf16_f32 %0, %1, %2" : "=v"(c3.u[3]) : "v"(a7[2]), "v"(a7[3]));
    *(short8v*)&lA[t * 8]        = c0.s8;
    *(short8v*)&lA[2048 + t * 8] = c1.s8;
    *(short8v*)&lA[4096 + t * 8] = c2.s8;
    *(short8v*)&lA[6144 + t * 8] = c3.s8;
    if (i < 11) {                               // a(i+1) reg prefetch
      a0 = *(const f32x4*)(gA + k0 + 64);
      a1 = *(const f32x4*)(gA + k0 + 68);
      a2 = *(const f32x4*)(gA + 32 * E_ + k0 + 64);
      a3 = *(const f32x4*)(gA + 32 * E_ + k0 + 68);
      a4 = *(const f32x4*)(gA + 64 * E_ + k0 + 64);
      a5 = *(const f32x4*)(gA + 64 * E_ + k0 + 68);
      a6 = *(const f32x4*)(gA + 96 * E_ + k0 + 64);
      a7 = *(const f32x4*)(gA + 96 * E_ + k0 + 68);
    }
    LG0;                                        // own ds_writes visible
    if (i < 11) { VM8; } else { VM0; }          // B(i) landed; a(i+1) in flight
    BAR;                                        // lA + lB staged block-wide
#pragma unroll
    for (int ks = 0; ks < 2; ++ks) {
      const int co = ks * 4;
      short8v aF[4], bF[4];
#pragma unroll
      for (int m = 0; m < 4; ++m) {
        const int r = wr + m * 16 + l15;
        aF[m] = *(const short8v*)&lA[r * 64 + (((co + lhi) ^ (l15 & 7)) << 3)];
      }
#pragma unroll
      for (int n = 0; n < 4; ++n) {
        const int r = wc + n * 16 + l15;
        bF[n] = *(const short8v*)&lB[r * 64 + (((co + lhi) ^ (l15 & 7)) << 3)];
      }
#pragma unroll
      for (int m = 0; m < 4; ++m)
#pragma unroll
        for (int n = 0; n < 4; ++n)
          acc[m][n] = __builtin_amdgcn_mfma_f32_16x16x32_bf16(aF[m], bF[n], acc[m][n], 0, 0, 0);
    }
  }

  const int nbase = nt * 128 + wc;
  unsigned short* dst = (nbase < 768) ? Qb : Kb;
  const int nb = (nbase < 768) ? nbase : nbase - 768;
#pragma unroll
  for (int m = 0; m < 4; ++m)
#pragma unroll
    for (int n = 0; n < 4; ++n)
#pragma unroll
      for (int r = 0; r < 4; ++r) {
        int M = mt * 128 + wr + m * 16 + lhi * 4 + r;
        int col = nb + n * 16 + l15;
        int h = col >> 6, d = col & 63;
        int b = M >> 11, s = M & (S_ - 1);
        dst[((((size_t)b * H_ + h) * S_ + s) << 6) + d] = f2bf(acc[m][n][r]);
      }
}

// Stage one 64-row K tile (8 KB) into LDS (256 threads), XOR-swizzled via
// pre-swizzled global source (rule #21: linear LDS dest).
// LDS[row][slot] (16B chunks, slot=0..7) = K[row][slot ^ (row&7)].
__device__ __forceinline__ void stageK(const unsigned short* __restrict__ Kbase, int t0,
                                       int tid, unsigned short* lbuf) {
  const int w = tid >> 6;
  const int r = tid >> 3;                       // 0..31
  const int c = (tid & 7) ^ (r & 7);            // inverse-swizzled source chunk
  const char* src = (const char*)Kbase + ((size_t)(t0 + r) << 7) + (c << 4);
  char* ldst = (char*)lbuf + (w << 10);         // wave-uniform; HW adds lane*16
  gload16(src, ldst);
  gload16(src + (32 << 7), ldst + 4096);        // rows 32..63, same swizzle
}

// 64 q-rows per wave: K-fragments read once from LDS feed 4 row-blocks.
// Diagonal self-exclusion folded in (bit-exact r1-r9).
__device__ __forceinline__ void computeTile64(const unsigned short* lbuf, const short8v q[4][2],
                                              f32x4 sp[4], bool isD, int l15, int lhi) {
  short8v kf[4][2];
  const int sw = l15 & 7;
#pragma unroll
  for (int f = 0; f < 4; ++f) {
    const char* p = (const char*)lbuf + ((f * 16 + l15) << 7);
    kf[f][0] = *(const short8v*)(p + ((lhi ^ sw) << 4));
    kf[f][1] = *(const short8v*)(p + (((lhi + 4) ^ sw) << 4));
  }
#pragma unroll
  for (int rb = 0; rb < 4; ++rb) {
    f32x4 acc[4] = {};
#pragma unroll
    for (int f = 0; f < 4; ++f) {
      acc[f] = __builtin_amdgcn_mfma_f32_16x16x32_bf16(q[rb][0], kf[f][0], acc[f], 0, 0, 0);
      acc[f] = __builtin_amdgcn_mfma_f32_16x16x32_bf16(q[rb][1], kf[f][1], acc[f], 0, 0, 0);
    }
#pragma unroll
    for (int f = 0; f < 4; ++f) {
      f32x4 e;
#pragma unroll
      for (int r = 0; r < 4; ++r) e[r] = __builtin_amdgcn_exp2f(acc[f][r]);
      if (isD && f == rb) {
#pragma unroll
        for (int r = 0; r < 4; ++r)
          if (l15 == lhi * 4 + r) e[r] = 0.f;
      }
      sp[rb] += e;                        // v_pk_add_f32 x2
    }
  }
}

// LSE row sums. r10: occupancy unlock -- 2-buffer rotation (16 KB LDS, was
// 24) + __launch_bounds__(256,8) pinning VGPR<=64 (r0 ran this compute
// structure at 64) -> 8 blocks/CU (32 waves) vs 6. Schedule is semantically
// the proven r0 pipeline: at VM0 only the own tile-i loads are outstanding
// (stage(i+1) is issued AFTER the barrier), so the drain set equals r0's
// VM2, and stage(i+1) gets a full compute-tile to land. Buffer-reuse proof:
// lK[(i+1)&1] last read at compute(i-1) < BAR(i) < stage(i+1) issue.
__global__ __launch_bounds__(256, 8) void lse_kernel(const unsigned short* __restrict__ Qb,
                                                     const unsigned short* __restrict__ Kb,
                                                     float* __restrict__ rowsum) {
  __shared__ __align__(16) unsigned short lK[2][4096];   // 2 x 8 KB
  const int L = blockIdx.x + 8 * (blockIdx.y + 12 * blockIdx.z);  // 0..1535
  const int xcd = L & 7, j = L >> 3;      // hw round-robins wgid%8 -> XCD
  const int split = j & 3;
  const int st = (j >> 2) & 7;
  const int g = xcd + 8 * (j >> 5);       // (b,h) group, 0..47
  const int h = g % H_, b = g / H_;

  const int tid = threadIdx.x;
  const int wid = tid >> 6, lane = tid & 63;
  const int l15 = lane & 15, lhi = lane >> 4;
  const size_t hb = ((size_t)b * H_ + h) * S_;
  const unsigned short* Qbase = Qb + hb * D_;
  const unsigned short* Kbase = Kb + hb * D_;
  const int s0 = st * 256 + wid * 64;     // 64 rows per wave
  const int tb = split * 512;             // 8 tiles of 64

  short8v q[4][2];
#pragma unroll
  for (int rb = 0; rb < 4; ++rb) {
    const unsigned short* qr = Qbase + (size_t)(s0 + rb * 16 + l15) * D_ + lhi * 8;
    q[rb][0] = *(const short8v*)qr;
    q[rb][1] = *(const short8v*)(qr + 32);
  }

  // tile index (within this split's 8 tiles) holding this wave's diagonal
  const int dtile = ((s0 >> 9) == split) ? ((s0 - tb) >> 6) : -1;

  f32x4 sp[4] = {};                       // sp[rb][r] row partial sums
  stageK(Kbase, tb, tid, lK[0]);
#pragma unroll 1
  for (int i = 0; i < 8; ++i) {
    VM0;                                   // own tile-i loads done (nothing else in flight)
    BAR;                                   // tile-i visible block-wide; compute(i-1) done
    if (i < 7) stageK(Kbase, tb + (i + 1) * 64, tid, lK[(i + 1) & 1]);
    computeTile64(lK[i & 1], q, sp, i == dtile, l15, lhi);
  }

#pragma unroll
  for (int rb = 0; rb < 4; ++rb)
#pragma unroll
    for (int r = 0; r < 4; ++r) {
      float s = sp[rb][r];
#pragma unroll
      for (int off = 1; off < 16; off <<= 1) s += __shfl_xor(s, off, 64);
      if (l15 == 0)
        rowsum[(size_t)split * NROWS + hb + s0 + rb * 16 + lhi * 4 + r] = s;
    }
}

__global__ __launch_bounds__(256) void finish1_kernel(const float* __restrict__ rowsum,
                                                      const float* __restrict__ beta,
                                                      float* __restrict__ partial) {
  int row = blockIdx.x * 256 + threadIdx.x;
  float s = (rowsum[row] + rowsum[NROWS + row]) +
            (rowsum[2 * NROWS + row] + rowsum[3 * NROWS + row]);
  int h = (row >> 11) % H_;
  float c = __builtin_amdgcn_logf(s) * LN2 / beta[h];   // v_log_f32 = log2
#pragma unroll
  for (int off = 1; off < 64; off <<= 1) c += __shfl_xor(c, off, 64);
  __shared__ float wsum[4];
  int wid = threadIdx.x >> 6;
  if ((threadIdx.x & 63) == 0) wsum[wid] = c;
  __syncthreads();
  if (threadIdx.x == 0) partial[blockIdx.x] = wsum[0] + wsum[1] + wsum[2] + wsum[3];
}

__global__ __launch_bounds__(256) void finish2_kernel(const float* __restrict__ partial, int n,
                                                      float* __restrict__ out) {
  float s = 0.f;
  for (int i = threadIdx.x; i < n; i += 256) s += partial[i];
#pragma unroll
  for (int off = 1; off < 64; off <<= 1) s += __shfl_xor(s, off, 64);
  __shared__ float wsum[4];
  int wid = threadIdx.x >> 6;
  if ((threadIdx.x & 63) == 0) wsum[wid] = s;
  __syncthreads();
  if (threadIdx.x == 0) out[0] = -(wsum[0] + wsum[1] + wsum[2] + wsum[3]);
}

extern "C" void kernel_launch(void* const* d_in, const int* in_sizes, int n_in,
                              void* d_out, int out_size, void* d_ws, size_t ws_size,
                              hipStream_t stream) {
  const float* x    = (const float*)d_in[0];
  const float* wq   = (const float*)d_in[1];
  const float* wk   = (const float*)d_in[2];
  const float* beta = (const float*)d_in[3];

  char* ws = (char*)d_ws;
  const size_t wb_bytes = (size_t)2 * H_ * D_ * E_ * 2;    //  2,359,296
  const size_t qk_bytes = (size_t)B_ * H_ * S_ * D_ * 2;   // 12,582,912
  const size_t rs_bytes = (size_t)4 * NROWS * 4;           //   1,572,864
  unsigned short* wb = (unsigned short*)ws;
  unsigned short* Qb = (unsigned short*)(ws + wb_bytes);
  unsigned short* Kb = (unsigned short*)(ws + wb_bytes + qk_bytes);
  float* rowsum      = (float*)(ws + wb_bytes + 2 * qk_bytes);
  float* partial     = (float*)(ws + wb_bytes + 2 * qk_bytes + rs_bytes);

  int nw4 = (H_ * D_ * E_) / 4;
  cvt_w_kernel<<<(2 * nw4 + 255) / 256, 256, 0, stream>>>((const float4*)wq, (const float4*)wk,
                                                          beta, (ushort4*)wb, nw4);

  dim3 pgrid((B_ * S_) / 128, (2 * H_ * D_) / 128);   // 64 x 12
  proj_kernel<<<pgrid, 256, 0, stream>>>(x, wb, Qb, Kb);

  dim3 lgrid(S_ / 256, H_, B_ * 4);                    // 8 x 12 x 16 = 1536 blocks
  lse_kernel<<<lgrid, 256, 0, stream>>>(Qb, Kb, rowsum);

  finish1_kernel<<<NROWS / 256, 256, 0, stream>>>(rowsum, beta, partial);
  finish2_kernel<<<1, 256, 0, stream>>>(partial, NROWS / 256, (float*)d_out);
}

// Round 11
// 81.294 us; speedup vs baseline: 2.1199x; 2.1199x over previous
//
#include <hip/hip_runtime.h>
#include <hip/hip_bf16.h>

typedef __attribute__((ext_vector_type(8))) short short8v;
typedef __attribute__((ext_vector_type(4))) float f32x4;

static constexpr int B_ = 4, S_ = 2048, E_ = 768, H_ = 12, D_ = 64;
static constexpr int NROWS = B_ * H_ * S_;       // 98304
static constexpr int NFIN = NROWS / 256;         // 384 finish blocks
static constexpr float LOG2E = 1.44269504088896340736f;
static constexpr float LN2 = 0.69314718055994530942f;

typedef __attribute__((address_space(3))) unsigned int lds_u32;
typedef const __attribute__((address_space(1))) unsigned int glb_u32;

__device__ __forceinline__ void gload16(const void* g, void* l) {
  __builtin_amdgcn_global_load_lds((glb_u32*)g, (lds_u32*)l, 16, 0, 0);
}

#define VM0 asm volatile("s_waitcnt vmcnt(0)" ::: "memory")
#define VM2 asm volatile("s_waitcnt vmcnt(2)" ::: "memory")
#define VM4 asm volatile("s_waitcnt vmcnt(4)" ::: "memory")
#define VM8 asm volatile("s_waitcnt vmcnt(8)" ::: "memory")
#define LG0 asm volatile("s_waitcnt lgkmcnt(0)" ::: "memory")
#define BAR __builtin_amdgcn_s_barrier()

__device__ __forceinline__ unsigned short f2bf(float f) {
  union { float f; unsigned int u; } v; v.f = f;
  unsigned int u = v.u;
  unsigned int r = (u + 0x7fffu + ((u >> 16) & 1u)) >> 16;
  return (unsigned short)r;
}

// wb[1536][768]: rows 0..767 = beta[h]*log2e*W^Q; rows 768..1535 = W^K.
// Also zeroes the finish-kernel's arrival counter (runs first every launch).
__global__ __launch_bounds__(256) void cvt_w_kernel(const float4* __restrict__ wq,
                                                    const float4* __restrict__ wk,
                                                    const float* __restrict__ beta,
                                                    ushort4* __restrict__ wb, int n4,
                                                    unsigned int* __restrict__ cnt) {
  int i = blockIdx.x * 256 + threadIdx.x;
  if (i == 0) *cnt = 0;
  if (i < n4) {
    int row = i / (E_ / 4);
    float sc = beta[row >> 6] * LOG2E;
    float4 v = wq[i];
    ushort4 o;
    o.x = f2bf(v.x * sc); o.y = f2bf(v.y * sc); o.z = f2bf(v.z * sc); o.w = f2bf(v.w * sc);
    wb[i] = o;
  } else if (i < 2 * n4) {
    int j = i - n4;
    float4 v = wk[j];
    ushort4 o;
    o.x = f2bf(v.x); o.y = f2bf(v.y); o.z = f2bf(v.z); o.w = f2bf(v.w);
    wb[i] = o;
  }
}

// GEMM: C[8192,1536] = X[8192,768] * W[1536,768]^T, 128x128 tile, BK=64.
// (r9's best: 2-barrier schedule, barriers halved vs BK=32, grid-limited
// 3 blocks/CU so 32KB LDS is free; counted waits never drain to 0 until
// the last step. Byte-identical to r9.)
__global__ __launch_bounds__(256, 3) void proj_kernel(const float* __restrict__ x,
                                                      const unsigned short* __restrict__ wb,
                                                      unsigned short* __restrict__ Qb,
                                                      unsigned short* __restrict__ Kb) {
  __shared__ unsigned short lA[128 * 64];       // 16 KB bf16
  __shared__ unsigned short lB[128 * 64];       // 16 KB bf16
  const int mt = blockIdx.x, nt = blockIdx.y;
  const int t = threadIdx.x;
  const int wid = t >> 6, lane = t & 63, l15 = lane & 15, lhi = lane >> 4;
  const int wr = (wid >> 1) * 64, wc = (wid & 1) * 64;

  f32x4 acc[4][4] = {};

  const int r0 = t >> 3;                        // 0..31
  const int cs = (t & 7) ^ (r0 & 7);            // inverse-swizzled source chunk
  const float* gA = x + (size_t)(mt * 128 + r0) * E_ + cs * 8;
  const unsigned short* gB = wb + (size_t)(nt * 128 + r0) * E_ + cs * 8;

  f32x4 a0 = *(const f32x4*)(gA);
  f32x4 a1 = *(const f32x4*)(gA + 4);
  f32x4 a2 = *(const f32x4*)(gA + 32 * E_);
  f32x4 a3 = *(const f32x4*)(gA + 32 * E_ + 4);
  f32x4 a4 = *(const f32x4*)(gA + 64 * E_);
  f32x4 a5 = *(const f32x4*)(gA + 64 * E_ + 4);
  f32x4 a6 = *(const f32x4*)(gA + 96 * E_);
  f32x4 a7 = *(const f32x4*)(gA + 96 * E_ + 4);

#pragma unroll 1
  for (int i = 0; i < 12; ++i) {
    const int k0 = i * 64;
    BAR;                                        // compute(i-1) done: lA/lB reusable
    gload16(gB + k0,            &lB[t * 8]);
    gload16(gB + 32 * E_ + k0,  &lB[2048 + t * 8]);
    gload16(gB + 64 * E_ + k0,  &lB[4096 + t * 8]);
    gload16(gB + 96 * E_ + k0,  &lB[6144 + t * 8]);
    VM4;                                        // a(i) landed; B(i) in flight
    union { short8v s8; unsigned int u[4]; } c0, c1, c2, c3;
    asm("v_cvt_pk_bf16_f32 %0, %1, %2" : "=v"(c0.u[0]) : "v"(a0[0]), "v"(a0[1]));
    asm("v_cvt_pk_bf16_f32 %0, %1, %2" : "=v"(c0.u[1]) : "v"(a0[2]), "v"(a0[3]));
    asm("v_cvt_pk_bf16_f32 %0, %1, %2" : "=v"(c0.u[2]) : "v"(a1[0]), "v"(a1[1]));
    asm("v_cvt_pk_bf16_f32 %0, %1, %2" : "=v"(c0.u[3]) : "v"(a1[2]), "v"(a1[3]));
    asm("v_cvt_pk_bf16_f32 %0, %1, %2" : "=v"(c1.u[0]) : "v"(a2[0]), "v"(a2[1]));
    asm("v_cvt_pk_bf16_f32 %0, %1, %2" : "=v"(c1.u[1]) : "v"(a2[2]), "v"(a2[3]));
    asm("v_cvt_pk_bf16_f32 %0, %1, %2" : "=v"(c1.u[2]) : "v"(a3[0]), "v"(a3[1]));
    asm("v_cvt_pk_bf16_f32 %0, %1, %2" : "=v"(c1.u[3]) : "v"(a3[2]), "v"(a3[3]));
    asm("v_cvt_pk_bf16_f32 %0, %1, %2" : "=v"(c2.u[0]) : "v"(a4[0]), "v"(a4[1]));
    asm("v_cvt_pk_bf16_f32 %0, %1, %2" : "=v"(c2.u[1]) : "v"(a4[2]), "v"(a4[3]));
    asm("v_cvt_pk_bf16_f32 %0, %1, %2" : "=v"(c2.u[2]) : "v"(a5[0]), "v"(a5[1]));
    asm("v_cvt_pk_bf16_f32 %0, %1, %2" : "=v"(c2.u[3]) : "v"(a5[2]), "v"(a5[3]));
    asm("v_cvt_pk_bf16_f32 %0, %1, %2" : "=v"(c3.u[0]) : "v"(a6[0]), "v"(a6[1]));
    asm("v_cvt_pk_bf16_f32 %0, %1, %2" : "=v"(c3.u[1]) : "v"(a6[2]), "v"(a6[3]));
    asm("v_cvt_pk_bf16_f32 %0, %1, %2" : "=v"(c3.u[2]) : "v"(a7[0]), "v"(a7[1]));
    asm("v_cvt_pk_bf16_f32 %0, %1, %2" : "=v"(c3.u[3]) : "v"(a7[2]), "v"(a7[3]));
    *(short8v*)&lA[t * 8]        = c0.s8;
    *(short8v*)&lA[2048 + t * 8] = c1.s8;
    *(short8v*)&lA[4096 + t * 8] = c2.s8;
    *(short8v*)&lA[6144 + t * 8] = c3.s8;
    if (i < 11) {                               // a(i+1) reg prefetch
      a0 = *(const f32x4*)(gA + k0 + 64);
      a1 = *(const f32x4*)(gA + k0 + 68);
      a2 = *(const f32x4*)(gA + 32 * E_ + k0 + 64);
      a3 = *(const f32x4*)(gA + 32 * E_ + k0 + 68);
      a4 = *(const f32x4*)(gA + 64 * E_ + k0 + 64);
      a5 = *(const f32x4*)(gA + 64 * E_ + k0 + 68);
      a6 = *(const f32x4*)(gA + 96 * E_ + k0 + 64);
      a7 = *(const f32x4*)(gA + 96 * E_ + k0 + 68);
    }
    LG0;                                        // own ds_writes visible
    if (i < 11) { VM8; } else { VM0; }          // B(i) landed; a(i+1) in flight
    BAR;                                        // lA + lB staged block-wide
#pragma unroll
    for (int ks = 0; ks < 2; ++ks) {
      const int co = ks * 4;
      short8v aF[4], bF[4];
#pragma unroll
      for (int m = 0; m < 4; ++m) {
        const int r = wr + m * 16 + l15;
        aF[m] = *(const short8v*)&lA[r * 64 + (((co + lhi) ^ (l15 & 7)) << 3)];
      }
#pragma unroll
      for (int n = 0; n < 4; ++n) {
        const int r = wc + n * 16 + l15;
        bF[n] = *(const short8v*)&lB[r * 64 + (((co + lhi) ^ (l15 & 7)) << 3)];
      }
#pragma unroll
      for (int m = 0; m < 4; ++m)
#pragma unroll
        for (int n = 0; n < 4; ++n)
          acc[m][n] = __builtin_amdgcn_mfma_f32_16x16x32_bf16(aF[m], bF[n], acc[m][n], 0, 0, 0);
    }
  }

  const int nbase = nt * 128 + wc;
  unsigned short* dst = (nbase < 768) ? Qb : Kb;
  const int nb = (nbase < 768) ? nbase : nbase - 768;
#pragma unroll
  for (int m = 0; m < 4; ++m)
#pragma unroll
    for (int n = 0; n < 4; ++n)
#pragma unroll
      for (int r = 0; r < 4; ++r) {
        int M = mt * 128 + wr + m * 16 + lhi * 4 + r;
        int col = nb + n * 16 + l15;
        int h = col >> 6, d = col & 63;
        int b = M >> 11, s = M & (S_ - 1);
        dst[((((size_t)b * H_ + h) * S_ + s) << 6) + d] = f2bf(acc[m][n][r]);
      }
}

// Stage one 64-row K tile (8 KB) into LDS (256 threads), XOR-swizzled via
// pre-swizzled global source (rule #21: linear LDS dest).
// LDS[row][slot] (16B chunks, slot=0..7) = K[row][slot ^ (row&7)].
__device__ __forceinline__ void stageK(const unsigned short* __restrict__ Kbase, int t0,
                                       int tid, unsigned short* lbuf) {
  const int w = tid >> 6;
  const int r = tid >> 3;                       // 0..31
  const int c = (tid & 7) ^ (r & 7);            // inverse-swizzled source chunk
  const char* src = (const char*)Kbase + ((size_t)(t0 + r) << 7) + (c << 4);
  char* ldst = (char*)lbuf + (w << 10);         // wave-uniform; HW adds lane*16
  gload16(src, ldst);
  gload16(src + (32 << 7), ldst + 4096);        // rows 32..63, same swizzle
}

// 64 q-rows per wave: K-fragments read once from LDS feed 4 row-blocks.
// Diagonal self-exclusion folded in (bit-exact r1-r9).
__device__ __forceinline__ void computeTile64(const unsigned short* lbuf, const short8v q[4][2],
                                              f32x4 sp[4], bool isD, int l15, int lhi) {
  short8v kf[4][2];
  const int sw = l15 & 7;
#pragma unroll
  for (int f = 0; f < 4; ++f) {
    const char* p = (const char*)lbuf + ((f * 16 + l15) << 7);
    kf[f][0] = *(const short8v*)(p + ((lhi ^ sw) << 4));
    kf[f][1] = *(const short8v*)(p + (((lhi + 4) ^ sw) << 4));
  }
#pragma unroll
  for (int rb = 0; rb < 4; ++rb) {
    f32x4 acc[4] = {};
#pragma unroll
    for (int f = 0; f < 4; ++f) {
      acc[f] = __builtin_amdgcn_mfma_f32_16x16x32_bf16(q[rb][0], kf[f][0], acc[f], 0, 0, 0);
      acc[f] = __builtin_amdgcn_mfma_f32_16x16x32_bf16(q[rb][1], kf[f][1], acc[f], 0, 0, 0);
    }
#pragma unroll
    for (int f = 0; f < 4; ++f) {
      f32x4 e;
#pragma unroll
      for (int r = 0; r < 4; ++r) e[r] = __builtin_amdgcn_exp2f(acc[f][r]);
      if (isD && f == rb) {
#pragma unroll
        for (int r = 0; r < 4; ++r)
          if (l15 == lhi * 4 + r) e[r] = 0.f;
      }
      sp[rb] += e;                        // v_pk_add_f32 x2
    }
  }
}

// LSE row sums -- byte-identical to the proven r9 artifact (45.2us).
// r10 lesson: VGPR ~80 is lse's true register need; forcing 64 via
// __launch_bounds__ spilled to scratch (FETCH 12->339 MB, 3x slower).
// Occupancy lever closed both directions (r3: more regs loses; r10:
// fewer spills). 3-buffer rotation, VM2, one barrier per tile.
__global__ __launch_bounds__(256) void lse_kernel(const unsigned short* __restrict__ Qb,
                                                  const unsigned short* __restrict__ Kb,
                                                  float* __restrict__ rowsum) {
  __shared__ __align__(16) unsigned short lK[3][4096];   // 3 x 8 KB
  const int L = blockIdx.x + 8 * (blockIdx.y + 12 * blockIdx.z);  // 0..1535
  const int xcd = L & 7, j = L >> 3;      // hw round-robins wgid%8 -> XCD
  const int split = j & 3;
  const int st = (j >> 2) & 7;
  const int g = xcd + 8 * (j >> 5);       // (b,h) group, 0..47
  const int h = g % H_, b = g / H_;

  const int tid = threadIdx.x;
  const int wid = tid >> 6, lane = tid & 63;
  const int l15 = lane & 15, lhi = lane >> 4;
  const size_t hb = ((size_t)b * H_ + h) * S_;
  const unsigned short* Qbase = Qb + hb * D_;
  const unsigned short* Kbase = Kb + hb * D_;
  const int s0 = st * 256 + wid * 64;     // 64 rows per wave
  const int tb = split * 512;             // 8 tiles of 64

  short8v q[4][2];
#pragma unroll
  for (int rb = 0; rb < 4; ++rb) {
    const unsigned short* qr = Qbase + (size_t)(s0 + rb * 16 + l15) * D_ + lhi * 8;
    q[rb][0] = *(const short8v*)qr;
    q[rb][1] = *(const short8v*)(qr + 32);
  }

  // tile index (within this split's 8 tiles) holding this wave's diagonal
  const int dtile = ((s0 >> 9) == split) ? ((s0 - tb) >> 6) : -1;

  f32x4 sp[4] = {};                       // sp[rb][r] row partial sums
  stageK(Kbase, tb, tid, lK[0]);
  stageK(Kbase, tb + 64, tid, lK[1]);
  int bi = 0;
#pragma unroll 1
  for (int i = 0; i < 7; ++i) {
    VM2;                                   // own tile-i loads done (only i+1 in flight)
    BAR;                                   // tile-i fully visible; compute(i-1) done
    if (i < 6) {
      int bs_ = bi + 2; if (bs_ >= 3) bs_ -= 3;
      stageK(Kbase, tb + (i + 2) * 64, tid, lK[bs_]);
    }
    computeTile64(lK[bi], q, sp, i == dtile, l15, lhi);
    if (++bi == 3) bi = 0;
  }
  VM0; BAR;
  computeTile64(lK[bi], q, sp, 7 == dtile, l15, lhi);

#pragma unroll
  for (int rb = 0; rb < 4; ++rb)
#pragma unroll
    for (int r = 0; r < 4; ++r) {
      float s = sp[rb][r];
#pragma unroll
      for (int off = 1; off < 16; off <<= 1) s += __shfl_xor(s, off, 64);
      if (l15 == 0)
        rowsum[(size_t)split * NROWS + hb + s0 + rb * 16 + lhi * 4 + r] = s;
    }
}

// Fused finish: per-block partial energy + last-block final reduction
// (store partial -> threadfence -> atomicAdd counter -> last arrival sums).
// Counter is zeroed by cvt_w_kernel at the start of every launch.
__global__ __launch_bounds__(256) void finish_kernel(const float* __restrict__ rowsum,
                                                     const float* __restrict__ beta,
                                                     float* __restrict__ partial,
                                                     unsigned int* __restrict__ cnt,
                                                     float* __restrict__ out) {
  int row = blockIdx.x * 256 + threadIdx.x;
  float s = (rowsum[row] + rowsum[NROWS + row]) +
            (rowsum[2 * NROWS + row] + rowsum[3 * NROWS + row]);
  int h = (row >> 11) % H_;
  float c = __builtin_amdgcn_logf(s) * LN2 / beta[h];   // v_log_f32 = log2
#pragma unroll
  for (int off = 1; off < 64; off <<= 1) c += __shfl_xor(c, off, 64);
  __shared__ float wsum[4];
  __shared__ unsigned int arrive;
  int wid = threadIdx.x >> 6;
  if ((threadIdx.x & 63) == 0) wsum[wid] = c;
  __syncthreads();
  if (threadIdx.x == 0) {
    partial[blockIdx.x] = wsum[0] + wsum[1] + wsum[2] + wsum[3];
    __threadfence();                      // partial visible device-wide
    arrive = atomicAdd(cnt, 1u);          // device-scope (m20)
  }
  __syncthreads();
  if (arrive == NFIN - 1) {               // last block finalizes
    __threadfence();
    float t = 0.f;
    const volatile float* vp = partial;
    for (int i = threadIdx.x; i < NFIN; i += 256) t += vp[i];
#pragma unroll
    for (int off = 1; off < 64; off <<= 1) t += __shfl_xor(t, off, 64);
    if ((threadIdx.x & 63) == 0) wsum[wid] = t;
    __syncthreads();
    if (threadIdx.x == 0) out[0] = -(wsum[0] + wsum[1] + wsum[2] + wsum[3]);
  }
}

extern "C" void kernel_launch(void* const* d_in, const int* in_sizes, int n_in,
                              void* d_out, int out_size, void* d_ws, size_t ws_size,
                              hipStream_t stream) {
  const float* x    = (const float*)d_in[0];
  const float* wq   = (const float*)d_in[1];
  const float* wk   = (const float*)d_in[2];
  const float* beta = (const float*)d_in[3];

  char* ws = (char*)d_ws;
  const size_t wb_bytes = (size_t)2 * H_ * D_ * E_ * 2;    //  2,359,296
  const size_t qk_bytes = (size_t)B_ * H_ * S_ * D_ * 2;   // 12,582,912
  const size_t rs_bytes = (size_t)4 * NROWS * 4;           //   1,572,864
  unsigned short* wb = (unsigned short*)ws;
  unsigned short* Qb = (unsigned short*)(ws + wb_bytes);
  unsigned short* Kb = (unsigned short*)(ws + wb_bytes + qk_bytes);
  float* rowsum      = (float*)(ws + wb_bytes + 2 * qk_bytes);
  float* partial     = (float*)(ws + wb_bytes + 2 * qk_bytes + rs_bytes);
  unsigned int* cnt  = (unsigned int*)(ws + wb_bytes + 2 * qk_bytes + rs_bytes +
                                       NFIN * sizeof(float));

  int nw4 = (H_ * D_ * E_) / 4;
  cvt_w_kernel<<<(2 * nw4 + 255) / 256, 256, 0, stream>>>((const float4*)wq, (const float4*)wk,
                                                          beta, (ushort4*)wb, nw4, cnt);

  dim3 pgrid((B_ * S_) / 128, (2 * H_ * D_) / 128);   // 64 x 12
  proj_kernel<<<pgrid, 256, 0, stream>>>(x, wb, Qb, Kb);

  dim3 lgrid(S_ / 256, H_, B_ * 4);                    // 8 x 12 x 16 = 1536 blocks
  lse_kernel<<<lgrid, 256, 0, stream>>>(Qb, Kb, rowsum);

  finish_kernel<<<NFIN, 256, 0, stream>>>(rowsum, beta, partial, cnt, (float*)d_out);
}

// Round 12
// 74.908 us; speedup vs baseline: 2.3006x; 1.0853x over previous
//
#include <hip/hip_runtime.h>
#include <hip/hip_bf16.h>

typedef __attribute__((ext_vector_type(8))) short short8v;
typedef __attribute__((ext_vector_type(4))) float f32x4;

static constexpr int B_ = 4, S_ = 2048, E_ = 768, H_ = 12, D_ = 64;
static constexpr int NROWS = B_ * H_ * S_;       // 98304
static constexpr float LOG2E = 1.44269504088896340736f;
static constexpr float LN2 = 0.69314718055994530942f;

typedef __attribute__((address_space(3))) unsigned int lds_u32;
typedef const __attribute__((address_space(1))) unsigned int glb_u32;

__device__ __forceinline__ void gload16(const void* g, void* l) {
  __builtin_amdgcn_global_load_lds((glb_u32*)g, (lds_u32*)l, 16, 0, 0);
}

#define VM0 asm volatile("s_waitcnt vmcnt(0)" ::: "memory")
#define VM2 asm volatile("s_waitcnt vmcnt(2)" ::: "memory")
#define VM4 asm volatile("s_waitcnt vmcnt(4)" ::: "memory")
#define VM8 asm volatile("s_waitcnt vmcnt(8)" ::: "memory")
#define LG0 asm volatile("s_waitcnt lgkmcnt(0)" ::: "memory")
#define BAR __builtin_amdgcn_s_barrier()

__device__ __forceinline__ unsigned short f2bf(float f) {
  union { float f; unsigned int u; } v; v.f = f;
  unsigned int u = v.u;
  unsigned int r = (u + 0x7fffu + ((u >> 16) & 1u)) >> 16;
  return (unsigned short)r;
}

// wb[1536][768]: rows 0..767 = beta[h]*log2e*W^Q; rows 768..1535 = W^K
__global__ __launch_bounds__(256) void cvt_w_kernel(const float4* __restrict__ wq,
                                                    const float4* __restrict__ wk,
                                                    const float* __restrict__ beta,
                                                    ushort4* __restrict__ wb, int n4) {
  int i = blockIdx.x * 256 + threadIdx.x;
  if (i < n4) {
    int row = i / (E_ / 4);
    float sc = beta[row >> 6] * LOG2E;
    float4 v = wq[i];
    ushort4 o;
    o.x = f2bf(v.x * sc); o.y = f2bf(v.y * sc); o.z = f2bf(v.z * sc); o.w = f2bf(v.w * sc);
    wb[i] = o;
  } else if (i < 2 * n4) {
    int j = i - n4;
    float4 v = wk[j];
    ushort4 o;
    o.x = f2bf(v.x); o.y = f2bf(v.y); o.z = f2bf(v.z); o.w = f2bf(v.w);
    wb[i] = o;
  }
}

// GEMM: C[8192,1536] = X[8192,768] * W[1536,768]^T, 128x128 tile, BK=64.
// (r9's best: 2-barrier schedule, barriers halved vs BK=32, grid-limited
// 3 blocks/CU so 32KB LDS is free; counted waits never drain to 0 until
// the last step. Byte-identical to r9.)
__global__ __launch_bounds__(256, 3) void proj_kernel(const float* __restrict__ x,
                                                      const unsigned short* __restrict__ wb,
                                                      unsigned short* __restrict__ Qb,
                                                      unsigned short* __restrict__ Kb) {
  __shared__ unsigned short lA[128 * 64];       // 16 KB bf16
  __shared__ unsigned short lB[128 * 64];       // 16 KB bf16
  const int mt = blockIdx.x, nt = blockIdx.y;
  const int t = threadIdx.x;
  const int wid = t >> 6, lane = t & 63, l15 = lane & 15, lhi = lane >> 4;
  const int wr = (wid >> 1) * 64, wc = (wid & 1) * 64;

  f32x4 acc[4][4] = {};

  const int r0 = t >> 3;                        // 0..31
  const int cs = (t & 7) ^ (r0 & 7);            // inverse-swizzled source chunk
  const float* gA = x + (size_t)(mt * 128 + r0) * E_ + cs * 8;
  const unsigned short* gB = wb + (size_t)(nt * 128 + r0) * E_ + cs * 8;

  f32x4 a0 = *(const f32x4*)(gA);
  f32x4 a1 = *(const f32x4*)(gA + 4);
  f32x4 a2 = *(const f32x4*)(gA + 32 * E_);
  f32x4 a3 = *(const f32x4*)(gA + 32 * E_ + 4);
  f32x4 a4 = *(const f32x4*)(gA + 64 * E_);
  f32x4 a5 = *(const f32x4*)(gA + 64 * E_ + 4);
  f32x4 a6 = *(const f32x4*)(gA + 96 * E_);
  f32x4 a7 = *(const f32x4*)(gA + 96 * E_ + 4);

#pragma unroll 1
  for (int i = 0; i < 12; ++i) {
    const int k0 = i * 64;
    BAR;                                        // compute(i-1) done: lA/lB reusable
    gload16(gB + k0,            &lB[t * 8]);
    gload16(gB + 32 * E_ + k0,  &lB[2048 + t * 8]);
    gload16(gB + 64 * E_ + k0,  &lB[4096 + t * 8]);
    gload16(gB + 96 * E_ + k0,  &lB[6144 + t * 8]);
    VM4;                                        // a(i) landed; B(i) in flight
    union { short8v s8; unsigned int u[4]; } c0, c1, c2, c3;
    asm("v_cvt_pk_bf16_f32 %0, %1, %2" : "=v"(c0.u[0]) : "v"(a0[0]), "v"(a0[1]));
    asm("v_cvt_pk_bf16_f32 %0, %1, %2" : "=v"(c0.u[1]) : "v"(a0[2]), "v"(a0[3]));
    asm("v_cvt_pk_bf16_f32 %0, %1, %2" : "=v"(c0.u[2]) : "v"(a1[0]), "v"(a1[1]));
    asm("v_cvt_pk_bf16_f32 %0, %1, %2" : "=v"(c0.u[3]) : "v"(a1[2]), "v"(a1[3]));
    asm("v_cvt_pk_bf16_f32 %0, %1, %2" : "=v"(c1.u[0]) : "v"(a2[0]), "v"(a2[1]));
    asm("v_cvt_pk_bf16_f32 %0, %1, %2" : "=v"(c1.u[1]) : "v"(a2[2]), "v"(a2[3]));
    asm("v_cvt_pk_bf16_f32 %0, %1, %2" : "=v"(c1.u[2]) : "v"(a3[0]), "v"(a3[1]));
    asm("v_cvt_pk_bf16_f32 %0, %1, %2" : "=v"(c1.u[3]) : "v"(a3[2]), "v"(a3[3]));
    asm("v_cvt_pk_bf16_f32 %0, %1, %2" : "=v"(c2.u[0]) : "v"(a4[0]), "v"(a4[1]));
    asm("v_cvt_pk_bf16_f32 %0, %1, %2" : "=v"(c2.u[1]) : "v"(a4[2]), "v"(a4[3]));
    asm("v_cvt_pk_bf16_f32 %0, %1, %2" : "=v"(c2.u[2]) : "v"(a5[0]), "v"(a5[1]));
    asm("v_cvt_pk_bf16_f32 %0, %1, %2" : "=v"(c2.u[3]) : "v"(a5[2]), "v"(a5[3]));
    asm("v_cvt_pk_bf16_f32 %0, %1, %2" : "=v"(c3.u[0]) : "v"(a6[0]), "v"(a6[1]));
    asm("v_cvt_pk_bf16_f32 %0, %1, %2" : "=v"(c3.u[1]) : "v"(a6[2]), "v"(a6[3]));
    asm("v_cvt_pk_bf16_f32 %0, %1, %2" : "=v"(c3.u[2]) : "v"(a7[0]), "v"(a7[1]));
    asm("v_cvt_pk_bf16_f32 %0, %1, %2" : "=v"(c3.u[3]) : "v"(a7[2]), "v"(a7[3]));
    *(short8v*)&lA[t * 8]        = c0.s8;
    *(short8v*)&lA[2048 + t * 8] = c1.s8;
    *(short8v*)&lA[4096 + t * 8] = c2.s8;
    *(short8v*)&lA[6144 + t * 8] = c3.s8;
    if (i < 11) {                               // a(i+1) reg prefetch
      a0 = *(const f32x4*)(gA + k0 + 64);
      a1 = *(const f32x4*)(gA + k0 + 68);
      a2 = *(const f32x4*)(gA + 32 * E_ + k0 + 64);
      a3 = *(const f32x4*)(gA + 32 * E_ + k0 + 68);
      a4 = *(const f32x4*)(gA + 64 * E_ + k0 + 64);
      a5 = *(const f32x4*)(gA + 64 * E_ + k0 + 68);
      a6 = *(const f32x4*)(gA + 96 * E_ + k0 + 64);
      a7 = *(const f32x4*)(gA + 96 * E_ + k0 + 68);
    }
    LG0;                                        // own ds_writes visible
    if (i < 11) { VM8; } else { VM0; }          // B(i) landed; a(i+1) in flight
    BAR;                                        // lA + lB staged block-wide
#pragma unroll
    for (int ks = 0; ks < 2; ++ks) {
      const int co = ks * 4;
      short8v aF[4], bF[4];
#pragma unroll
      for (int m = 0; m < 4; ++m) {
        const int r = wr + m * 16 + l15;
        aF[m] = *(const short8v*)&lA[r * 64 + (((co + lhi) ^ (l15 & 7)) << 3)];
      }
#pragma unroll
      for (int n = 0; n < 4; ++n) {
        const int r = wc + n * 16 + l15;
        bF[n] = *(const short8v*)&lB[r * 64 + (((co + lhi) ^ (l15 & 7)) << 3)];
      }
#pragma unroll
      for (int m = 0; m < 4; ++m)
#pragma unroll
        for (int n = 0; n < 4; ++n)
          acc[m][n] = __builtin_amdgcn_mfma_f32_16x16x32_bf16(aF[m], bF[n], acc[m][n], 0, 0, 0);
    }
  }

  const int nbase = nt * 128 + wc;
  unsigned short* dst = (nbase < 768) ? Qb : Kb;
  const int nb = (nbase < 768) ? nbase : nbase - 768;
#pragma unroll
  for (int m = 0; m < 4; ++m)
#pragma unroll
    for (int n = 0; n < 4; ++n)
#pragma unroll
      for (int r = 0; r < 4; ++r) {
        int M = mt * 128 + wr + m * 16 + lhi * 4 + r;
        int col = nb + n * 16 + l15;
        int h = col >> 6, d = col & 63;
        int b = M >> 11, s = M & (S_ - 1);
        dst[((((size_t)b * H_ + h) * S_ + s) << 6) + d] = f2bf(acc[m][n][r]);
      }
}

// Stage one 64-row K tile (8 KB) into LDS (256 threads), XOR-swizzled via
// pre-swizzled global source (rule #21: linear LDS dest).
// LDS[row][slot] (16B chunks, slot=0..7) = K[row][slot ^ (row&7)].
__device__ __forceinline__ void stageK(const unsigned short* __restrict__ Kbase, int t0,
                                       int tid, unsigned short* lbuf) {
  const int w = tid >> 6;
  const int r = tid >> 3;                       // 0..31
  const int c = (tid & 7) ^ (r & 7);            // inverse-swizzled source chunk
  const char* src = (const char*)Kbase + ((size_t)(t0 + r) << 7) + (c << 4);
  char* ldst = (char*)lbuf + (w << 10);         // wave-uniform; HW adds lane*16
  gload16(src, ldst);
  gload16(src + (32 << 7), ldst + 4096);        // rows 32..63, same swizzle
}

// 64 q-rows per wave: K-fragments read once from LDS feed 4 row-blocks.
// Diagonal self-exclusion folded in (bit-exact r1-r11).
__device__ __forceinline__ void computeTile64(const unsigned short* lbuf, const short8v q[4][2],
                                              f32x4 sp[4], bool isD, int l15, int lhi) {
  short8v kf[4][2];
  const int sw = l15 & 7;
#pragma unroll
  for (int f = 0; f < 4; ++f) {
    const char* p = (const char*)lbuf + ((f * 16 + l15) << 7);
    kf[f][0] = *(const short8v*)(p + ((lhi ^ sw) << 4));
    kf[f][1] = *(const short8v*)(p + (((lhi + 4) ^ sw) << 4));
  }
#pragma unroll
  for (int rb = 0; rb < 4; ++rb) {
    f32x4 acc[4] = {};
#pragma unroll
    for (int f = 0; f < 4; ++f) {
      acc[f] = __builtin_amdgcn_mfma_f32_16x16x32_bf16(q[rb][0], kf[f][0], acc[f], 0, 0, 0);
      acc[f] = __builtin_amdgcn_mfma_f32_16x16x32_bf16(q[rb][1], kf[f][1], acc[f], 0, 0, 0);
    }
#pragma unroll
    for (int f = 0; f < 4; ++f) {
      f32x4 e;
#pragma unroll
      for (int r = 0; r < 4; ++r) e[r] = __builtin_amdgcn_exp2f(acc[f][r]);
      if (isD && f == rb) {
#pragma unroll
        for (int r = 0; r < 4; ++r)
          if (l15 == lhi * 4 + r) e[r] = 0.f;
      }
      sp[rb] += e;                        // v_pk_add_f32 x2
    }
  }
}

// LSE row sums -- byte-identical to the proven r9 artifact (45.2us).
// Plateau evidence: occupancy closed both directions (r3 more regs loses;
// r10 fewer spills); schedule variants (LDS-free, reg-dbuf, 4-buf, 2-buf)
// all 45-160us. 3-buffer rotation, VM2, one barrier per tile.
__global__ __launch_bounds__(256) void lse_kernel(const unsigned short* __restrict__ Qb,
                                                  const unsigned short* __restrict__ Kb,
                                                  float* __restrict__ rowsum) {
  __shared__ __align__(16) unsigned short lK[3][4096];   // 3 x 8 KB
  const int L = blockIdx.x + 8 * (blockIdx.y + 12 * blockIdx.z);  // 0..1535
  const int xcd = L & 7, j = L >> 3;      // hw round-robins wgid%8 -> XCD
  const int split = j & 3;
  const int st = (j >> 2) & 7;
  const int g = xcd + 8 * (j >> 5);       // (b,h) group, 0..47
  const int h = g % H_, b = g / H_;

  const int tid = threadIdx.x;
  const int wid = tid >> 6, lane = tid & 63;
  const int l15 = lane & 15, lhi = lane >> 4;
  const size_t hb = ((size_t)b * H_ + h) * S_;
  const unsigned short* Qbase = Qb + hb * D_;
  const unsigned short* Kbase = Kb + hb * D_;
  const int s0 = st * 256 + wid * 64;     // 64 rows per wave
  const int tb = split * 512;             // 8 tiles of 64

  short8v q[4][2];
#pragma unroll
  for (int rb = 0; rb < 4; ++rb) {
    const unsigned short* qr = Qbase + (size_t)(s0 + rb * 16 + l15) * D_ + lhi * 8;
    q[rb][0] = *(const short8v*)qr;
    q[rb][1] = *(const short8v*)(qr + 32);
  }

  // tile index (within this split's 8 tiles) holding this wave's diagonal
  const int dtile = ((s0 >> 9) == split) ? ((s0 - tb) >> 6) : -1;

  f32x4 sp[4] = {};                       // sp[rb][r] row partial sums
  stageK(Kbase, tb, tid, lK[0]);
  stageK(Kbase, tb + 64, tid, lK[1]);
  int bi = 0;
#pragma unroll 1
  for (int i = 0; i < 7; ++i) {
    VM2;                                   // own tile-i loads done (only i+1 in flight)
    BAR;                                   // tile-i fully visible; compute(i-1) done
    if (i < 6) {
      int bs_ = bi + 2; if (bs_ >= 3) bs_ -= 3;
      stageK(Kbase, tb + (i + 2) * 64, tid, lK[bs_]);
    }
    computeTile64(lK[bi], q, sp, i == dtile, l15, lhi);
    if (++bi == 3) bi = 0;
  }
  VM0; BAR;
  computeTile64(lK[bi], q, sp, 7 == dtile, l15, lhi);

#pragma unroll
  for (int rb = 0; rb < 4; ++rb)
#pragma unroll
    for (int r = 0; r < 4; ++r) {
      float s = sp[rb][r];
#pragma unroll
      for (int off = 1; off < 16; off <<= 1) s += __shfl_xor(s, off, 64);
      if (l15 == 0)
        rowsum[(size_t)split * NROWS + hb + s0 + rb * 16 + lhi * 4 + r] = s;
    }
}

__global__ __launch_bounds__(256) void finish1_kernel(const float* __restrict__ rowsum,
                                                      const float* __restrict__ beta,
                                                      float* __restrict__ partial) {
  int row = blockIdx.x * 256 + threadIdx.x;
  float s = (rowsum[row] + rowsum[NROWS + row]) +
            (rowsum[2 * NROWS + row] + rowsum[3 * NROWS + row]);
  int h = (row >> 11) % H_;
  float c = __builtin_amdgcn_logf(s) * LN2 / beta[h];   // v_log_f32 = log2
#pragma unroll
  for (int off = 1; off < 64; off <<= 1) c += __shfl_xor(c, off, 64);
  __shared__ float wsum[4];
  int wid = threadIdx.x >> 6;
  if ((threadIdx.x & 63) == 0) wsum[wid] = c;
  __syncthreads();
  if (threadIdx.x == 0) partial[blockIdx.x] = wsum[0] + wsum[1] + wsum[2] + wsum[3];
}

__global__ __launch_bounds__(256) void finish2_kernel(const float* __restrict__ partial, int n,
                                                      float* __restrict__ out) {
  float s = 0.f;
  for (int i = threadIdx.x; i < n; i += 256) s += partial[i];
#pragma unroll
  for (int off = 1; off < 64; off <<= 1) s += __shfl_xor(s, off, 64);
  __shared__ float wsum[4];
  int wid = threadIdx.x >> 6;
  if ((threadIdx.x & 63) == 0) wsum[wid] = s;
  __syncthreads();
  if (threadIdx.x == 0) out[0] = -(wsum[0] + wsum[1] + wsum[2] + wsum[3]);
}

extern "C" void kernel_launch(void* const* d_in, const int* in_sizes, int n_in,
                              void* d_out, int out_size, void* d_ws, size_t ws_size,
                              hipStream_t stream) {
  const float* x    = (const float*)d_in[0];
  const float* wq   = (const float*)d_in[1];
  const float* wk   = (const float*)d_in[2];
  const float* beta = (const float*)d_in[3];

  char* ws = (char*)d_ws;
  const size_t wb_bytes = (size_t)2 * H_ * D_ * E_ * 2;    //  2,359,296
  const size_t qk_bytes = (size_t)B_ * H_ * S_ * D_ * 2;   // 12,582,912
  const size_t rs_bytes = (size_t)4 * NROWS * 4;           //   1,572,864
  unsigned short* wb = (unsigned short*)ws;
  unsigned short* Qb = (unsigned short*)(ws + wb_bytes);
  unsigned short* Kb = (unsigned short*)(ws + wb_bytes + qk_bytes);
  float* rowsum      = (float*)(ws + wb_bytes + 2 * qk_bytes);
  float* partial     = (float*)(ws + wb_bytes + 2 * qk_bytes + rs_bytes);

  int nw4 = (H_ * D_ * E_) / 4;
  cvt_w_kernel<<<(2 * nw4 + 255) / 256, 256, 0, stream>>>((const float4*)wq, (const float4*)wk,
                                                          beta, (ushort4*)wb, nw4);

  dim3 pgrid((B_ * S_) / 128, (2 * H_ * D_) / 128);   // 64 x 12
  proj_kernel<<<pgrid, 256, 0, stream>>>(x, wb, Qb, Kb);

  dim3 lgrid(S_ / 256, H_, B_ * 4);                    // 8 x 12 x 16 = 1536 blocks
  lse_kernel<<<lgrid, 256, 0, stream>>>(Qb, Kb, rowsum);

  finish1_kernel<<<NROWS / 256, 256, 0, stream>>>(rowsum, beta, partial);
  finish2_kernel<<<1, 256, 0, stream>>>(partial, NROWS / 256, (float*)d_out);
}